// Round 2
// baseline (1313.818 us; speedup 1.0000x reference)
//
#include <hip/hip_runtime.h>
#include <math.h>

#define NCLS 100
#define D 64
#define ACC_FLOATS (NCLS * D * 2 + NCLS)   // 12900 floats = 51.6 KB
#define BLK1 256
#define GRID1 768
#define UNROLL 8

// Native LDS float atomic add (bypasses hipcc's CAS-loop expansion of
// atomicAdd(float*) under default IEEE-denormal compile flags).
// byteoff = LDS byte offset; low 32 bits of a flat shared-pointer are the
// LDS offset on gfx9+ (shared aperture low word is 0).
__device__ __forceinline__ void lds_fadd(uint32_t byteoff, float v) {
    asm volatile("ds_add_f32 %0, %1" :: "v"(byteoff), "v"(v));
}

// Native global float atomic add (no return) — global_atomic_add_f32.
__device__ __forceinline__ void global_fadd(float* p, float v) {
    asm volatile("global_atomic_add_f32 %0, %1, off"
                 :: "v"((uint64_t)(uintptr_t)p), "v"(v));
}

// ---------------- Kernel 1: segmented sum / sumsq / count ----------------
__global__ __launch_bounds__(BLK1) void seg_stats_kernel(
    const float* __restrict__ pred, const int* __restrict__ idx,
    float* __restrict__ gacc, int nrows)
{
    __shared__ float sm[ACC_FLOATS];
    for (int i = threadIdx.x; i < ACC_FLOATS; i += BLK1) sm[i] = 0.0f;
    __syncthreads();

    const uint32_t smBase = (uint32_t)(uintptr_t)(&sm[0]);
    const uint32_t offSum = smBase;                          // [NCLS*D]
    const uint32_t offSq  = smBase + NCLS * D * 4;           // [NCLS*D]
    const uint32_t offCnt = smBase + 2 * NCLS * D * 4;       // [NCLS]

    const int lane = threadIdx.x & 63;
    int wid = (int)((blockIdx.x * blockDim.x + threadIdx.x) >> 6);
    wid = __builtin_amdgcn_readfirstlane(wid);
    const int nwaves = (GRID1 * BLK1) >> 6;

    const int chunk = (nrows + nwaves - 1) / nwaves;
    long long start = (long long)wid * chunk;
    long long end   = start + chunk;
    if (end > nrows) end = nrows;
    if (start > end) start = end;

    long long r = start;
    for (; r + UNROLL <= end; r += UNROLL) {
        int   cc[UNROLL];
        float vv[UNROLL];
        #pragma unroll
        for (int u = 0; u < UNROLL; ++u) cc[u] = idx[r + u];   // wave-uniform -> s_load
        #pragma unroll
        for (int u = 0; u < UNROLL; ++u)
            vv[u] = pred[(size_t)(r + u) * D + lane];          // coalesced 256B
        #pragma unroll
        for (int u = 0; u < UNROLL; ++u) {
            uint32_t o = (uint32_t)(cc[u] * D + lane) * 4u;
            lds_fadd(offSum + o, vv[u]);
            lds_fadd(offSq  + o, vv[u] * vv[u]);
        }
        if (lane == 0) {
            #pragma unroll
            for (int u = 0; u < UNROLL; ++u)
                lds_fadd(offCnt + (uint32_t)cc[u] * 4u, 1.0f);
        }
    }
    for (; r < end; ++r) {
        int c = idx[r];
        float v = pred[(size_t)r * D + lane];
        uint32_t o = (uint32_t)(c * D + lane) * 4u;
        lds_fadd(offSum + o, v);
        lds_fadd(offSq  + o, v * v);
        if (lane == 0) lds_fadd(offCnt + (uint32_t)c * 4u, 1.0f);
    }

    // drain our untracked ds ops before the barrier, then reduce to global
    asm volatile("s_waitcnt lgkmcnt(0)" ::: "memory");
    __syncthreads();

    for (int i = threadIdx.x; i < ACC_FLOATS; i += BLK1)
        global_fadd(&gacc[i], sm[i]);
}

// ---------------- Kernel 2: finalize (means/std/cov/pair distances) ------
#define MSTR 68   // padded stride: 16B-aligned, breaks bank alignment

__global__ __launch_bounds__(1024) void finalize_kernel(
    const float* __restrict__ gacc, float* __restrict__ out)
{
    __shared__ float mean_s[NCLS * MSTR];
    __shared__ float colstd[D];
    __shared__ float norms[NCLS];
    __shared__ float redSum[16], redMin[16];
    __shared__ float s_cov;

    const float* gSum = gacc;
    const float* gSq  = gacc + NCLS * D;
    const float* gCnt = gacc + 2 * NCLS * D;

    for (int d = threadIdx.x; d < D; d += 1024) colstd[d] = 0.0f;
    __syncthreads();

    // mean, std, colstd accumulation (colstd via native LDS fadd too)
    for (int i = threadIdx.x; i < NCLS * D; i += 1024) {
        int c = i >> 6, d = i & 63;
        float cnt = gCnt[c];
        float m   = gSum[i] / cnt;
        float var = (gSq[i] - cnt * m * m) / (cnt - 1.0f);
        float sd  = sqrtf(fmaxf(var, 0.0f));
        mean_s[c * MSTR + d] = m;
        lds_fadd((uint32_t)(uintptr_t)(&colstd[d]), sd);
    }
    asm volatile("s_waitcnt lgkmcnt(0)" ::: "memory");
    __syncthreads();

    // cov = sum_d (colstd[d]^2) / C   (wave 0 only)
    if (threadIdx.x < 64) {
        float v = colstd[threadIdx.x];
        v = v * v;
        for (int o = 32; o; o >>= 1) v += __shfl_down(v, o);
        if (threadIdx.x == 0) s_cov = v / (float)NCLS;
    }

    // norms[c] = |mean_c|^2
    for (int c = threadIdx.x; c < NCLS; c += 1024) {
        const float4* mp = (const float4*)&mean_s[c * MSTR];
        float n = 0.0f;
        #pragma unroll
        for (int d4 = 0; d4 < D / 4; ++d4) {
            float4 a = mp[d4];
            n += a.x * a.x + a.y * a.y + a.z * a.z + a.w * a.w;
        }
        norms[c] = n;
    }
    __syncthreads();

    // pair distances over lower triangle (i>j), 4950 pairs
    const int n_pairs = NCLS * (NCLS - 1) / 2;
    float lsum = 0.0f, lmin = INFINITY;
    for (int p = threadIdx.x; p < n_pairs; p += 1024) {
        int i = (int)((1.0f + sqrtf(1.0f + 8.0f * (float)p)) * 0.5f);
        while (i * (i - 1) / 2 > p) --i;
        while ((i + 1) * i / 2 <= p) ++i;
        int j = p - i * (i - 1) / 2;

        const float4* mi = (const float4*)&mean_s[i * MSTR];
        const float4* mj = (const float4*)&mean_s[j * MSTR];
        float dot = 0.0f;
        #pragma unroll
        for (int d4 = 0; d4 < D / 4; ++d4) {
            float4 a = mi[d4], b = mj[d4];
            dot += a.x * b.x + a.y * b.y + a.z * b.z + a.w * b.w;
        }
        float dist = norms[i] + norms[j] - 2.0f * dot;
        lsum += dist;
        lmin = fminf(lmin, dist);
    }

    // block reduce (16 waves)
    for (int o = 32; o; o >>= 1) {
        lsum += __shfl_down(lsum, o);
        lmin = fminf(lmin, __shfl_down(lmin, o));
    }
    int w = threadIdx.x >> 6;
    if ((threadIdx.x & 63) == 0) { redSum[w] = lsum; redMin[w] = lmin; }
    __syncthreads();

    if (threadIdx.x == 0) {
        float S = 0.0f, M = INFINITY;
        for (int k = 0; k < 16; ++k) { S += redSum[k]; M = fminf(M, redMin[k]); }
        float md  = S / (float)n_pairs;
        float cov = s_cov;
        float e   = 8.0f - md;
        float loss = 1.0f * cov + 0.1f * e * e;   // C_COEF = 0
        out[0] = loss;
        out[1] = md;
        out[2] = M;
        out[3] = cov;
    }
}

extern "C" void kernel_launch(void* const* d_in, const int* in_sizes, int n_in,
                              void* d_out, int out_size, void* d_ws, size_t ws_size,
                              hipStream_t stream) {
    const float* pred = (const float*)d_in[0];
    const int*   gidx = (const int*)d_in[1];
    float* out  = (float*)d_out;
    float* gacc = (float*)d_ws;
    int nrows = in_sizes[1];   // 2,000,000 rows

    hipMemsetAsync(gacc, 0, ACC_FLOATS * sizeof(float), stream);
    seg_stats_kernel<<<GRID1, BLK1, 0, stream>>>(pred, gidx, gacc, nrows);
    finalize_kernel<<<1, 1024, 0, stream>>>(gacc, out);
}

// Round 3
// 337.660 us; speedup vs baseline: 3.8909x; 3.8909x over previous
//
#include <hip/hip_runtime.h>
#include <math.h>

#define NCLS 100
#define D 64
#define GACC_FLOATS (NCLS * D * 2 + NCLS)   // 12900
#define G1 768
#define BLK 256

typedef __attribute__((ext_vector_type(8)))  short bf16x8;
typedef __attribute__((ext_vector_type(16))) float f32x16;

#define ZV16 {0.f,0.f,0.f,0.f,0.f,0.f,0.f,0.f,0.f,0.f,0.f,0.f,0.f,0.f,0.f,0.f}

union B8 { uint32_t u[4]; bf16x8 v; };

// f32 -> bf16 round-to-nearest-even (inputs are finite normals)
__device__ __forceinline__ ushort f2bf(float x) {
    uint32_t u = __float_as_uint(x);
    return (ushort)((u + 0x7FFFu + ((u >> 16) & 1u)) >> 16);
}
__device__ __forceinline__ uint32_t pk2(float lo, float hi) {
    return (uint32_t)f2bf(lo) | ((uint32_t)f2bf(hi) << 16);
}

__device__ __forceinline__ void global_fadd(float* p, float v) {
    asm volatile("global_atomic_add_f32 %0, %1, off"
                 :: "v"((uint64_t)(uintptr_t)p), "v"(v));
}

// ---------------- Kernel 1: segmented stats via one-hot MFMA --------------
// sums = onehot(idx)^T @ pred ; sq = onehot^T @ pred^2 ; cnt = onehot^T @ 1
// A tile: 32(M=classes) x 16(K=rows); wave w owns classes [32w, 32w+32).
// A layout: row m = lane&31, k = (lane>>5)*8 + e. B: col n = lane&31, same k.
// C/D layout (verified m74/m101): col=lane&31, row=(reg&3)+8*(reg>>2)+4*(lane>>5)
__global__ __launch_bounds__(BLK, 3) void seg_mfma_kernel(
    const float* __restrict__ pred, const int* __restrict__ idx,
    float* __restrict__ part,   // [GACC_FLOATS][G1]  (partials path)
    float* __restrict__ gacc,   // [GACC_FLOATS]      (atomic path)
    int nrows, int atomicPath)
{
    const int bid   = blockIdx.x;
    const int lane  = threadIdx.x & 63;
    const int w     = threadIdx.x >> 6;   // 0..3 -> class tile
    const int col   = lane & 31;          // n for B/D, m-row for A
    const int kg    = lane >> 5;          // k-group 0/1
    const int mycls = w * 32 + col;

    f32x16 aS0 = ZV16, aS1 = ZV16, aQ0 = ZV16, aQ1 = ZV16, aC = ZV16;

    B8 ob; ob.u[0] = 0x3F803F80u; ob.u[1] = 0x3F803F80u;
           ob.u[2] = 0x3F803F80u; ob.u[3] = 0x3F803F80u;
    const bf16x8 ones = ob.v;

    const size_t nslab = (size_t)nrows >> 4;
    size_t s0 = (size_t)bid * nslab / G1;
    size_t s1 = ((size_t)bid + 1) * nslab / G1;

    for (size_t s = s0; s < s1; ++s) {
        const size_t kb = s << 4;
        const int* ip = idx + kb + (size_t)kg * 8;
        const int4 i0 = *(const int4*)ip;
        const int4 i1 = *(const int4*)(ip + 4);

        B8 ab;
        ab.u[0] = (i0.x==mycls?0x3F80u:0u) | (i0.y==mycls?0x3F800000u:0u);
        ab.u[1] = (i0.z==mycls?0x3F80u:0u) | (i0.w==mycls?0x3F800000u:0u);
        ab.u[2] = (i1.x==mycls?0x3F80u:0u) | (i1.y==mycls?0x3F800000u:0u);
        ab.u[3] = (i1.z==mycls?0x3F80u:0u) | (i1.w==mycls?0x3F800000u:0u);

        const float* pb = pred + ((kb + (size_t)kg * 8) << 6) + col;
        float v[8], u[8];
        #pragma unroll
        for (int e = 0; e < 8; ++e) { v[e] = pb[(size_t)e * 64]; u[e] = pb[(size_t)e * 64 + 32]; }

        B8 b0, b1, q0, q1;
        #pragma unroll
        for (int e = 0; e < 4; ++e) {
            b0.u[e] = pk2(v[2*e], v[2*e+1]);
            b1.u[e] = pk2(u[2*e], u[2*e+1]);
            q0.u[e] = pk2(v[2*e]*v[2*e], v[2*e+1]*v[2*e+1]);
            q1.u[e] = pk2(u[2*e]*u[2*e], u[2*e+1]*u[2*e+1]);
        }
        aS0 = __builtin_amdgcn_mfma_f32_32x32x16_bf16(ab.v, b0.v, aS0, 0, 0, 0);
        aS1 = __builtin_amdgcn_mfma_f32_32x32x16_bf16(ab.v, b1.v, aS1, 0, 0, 0);
        aQ0 = __builtin_amdgcn_mfma_f32_32x32x16_bf16(ab.v, q0.v, aQ0, 0, 0, 0);
        aQ1 = __builtin_amdgcn_mfma_f32_32x32x16_bf16(ab.v, q1.v, aQ1, 0, 0, 0);
        aC  = __builtin_amdgcn_mfma_f32_32x32x16_bf16(ab.v, ones, aC,  0, 0, 0);
    }

    // tail rows (nrows % 16) handled by last block, masked
    if (bid == G1 - 1 && (nrows & 15)) {
        const size_t kb = nslab << 4;
        int   c[8]; float v[8], u[8];
        #pragma unroll
        for (int e = 0; e < 8; ++e) {
            size_t kk = kb + (size_t)kg * 8 + e;
            bool ok = kk < (size_t)nrows;
            c[e] = ok ? idx[kk] : -1;
            v[e] = ok ? pred[(kk << 6) + col] : 0.0f;
            u[e] = ok ? pred[(kk << 6) + 32 + col] : 0.0f;
        }
        B8 ab, b0, b1, q0, q1;
        #pragma unroll
        for (int e = 0; e < 4; ++e) {
            ab.u[e] = (c[2*e]==mycls?0x3F80u:0u) | (c[2*e+1]==mycls?0x3F800000u:0u);
            b0.u[e] = pk2(v[2*e], v[2*e+1]);
            b1.u[e] = pk2(u[2*e], u[2*e+1]);
            q0.u[e] = pk2(v[2*e]*v[2*e], v[2*e+1]*v[2*e+1]);
            q1.u[e] = pk2(u[2*e]*u[2*e], u[2*e+1]*u[2*e+1]);
        }
        aS0 = __builtin_amdgcn_mfma_f32_32x32x16_bf16(ab.v, b0.v, aS0, 0, 0, 0);
        aS1 = __builtin_amdgcn_mfma_f32_32x32x16_bf16(ab.v, b1.v, aS1, 0, 0, 0);
        aQ0 = __builtin_amdgcn_mfma_f32_32x32x16_bf16(ab.v, q0.v, aQ0, 0, 0, 0);
        aQ1 = __builtin_amdgcn_mfma_f32_32x32x16_bf16(ab.v, q1.v, aQ1, 0, 0, 0);
        aC  = __builtin_amdgcn_mfma_f32_32x32x16_bf16(ab.v, ones, aC,  0, 0, 0);
    }

    // epilogue: scatter per-block partials (or atomics)
    #pragma unroll
    for (int reg = 0; reg < 16; ++reg) {
        int row = (reg & 3) + 8 * (reg >> 2) + 4 * kg;
        int gm  = w * 32 + row;
        if (gm < NCLS) {
            int pS0 = gm * D + col;
            int pS1 = gm * D + 32 + col;
            if (!atomicPath) {
                part[(size_t)pS0 * G1 + bid]              = aS0[reg];
                part[(size_t)pS1 * G1 + bid]              = aS1[reg];
                part[(size_t)(NCLS*D + pS0) * G1 + bid]   = aQ0[reg];
                part[(size_t)(NCLS*D + pS1) * G1 + bid]   = aQ1[reg];
                if (col == 0)
                    part[(size_t)(2*NCLS*D + gm) * G1 + bid] = aC[reg];
            } else {
                global_fadd(&gacc[pS0], aS0[reg]);
                global_fadd(&gacc[pS1], aS1[reg]);
                global_fadd(&gacc[NCLS*D + pS0], aQ0[reg]);
                global_fadd(&gacc[NCLS*D + pS1], aQ1[reg]);
                if (col == 0) global_fadd(&gacc[2*NCLS*D + gm], aC[reg]);
            }
        }
    }
}

// ---------------- Kernel 1b: reduce partials across blocks ---------------
__global__ __launch_bounds__(256) void reduce_kernel(
    const float* __restrict__ part, float* __restrict__ gacc)
{
    int pos = blockIdx.x * 4 + (threadIdx.x >> 6);
    if (pos >= GACC_FLOATS) return;
    int lane = threadIdx.x & 63;
    const float* p = part + (size_t)pos * G1;
    float sum = 0.0f;
    for (int b = lane; b < G1; b += 64) sum += p[b];
    for (int o = 32; o; o >>= 1) sum += __shfl_down(sum, o);
    if (lane == 0) gacc[pos] = sum;
}

// ---------------- Kernel 2: finalize (unchanged, verified) ---------------
#define MSTR 68

__device__ __forceinline__ void lds_fadd(uint32_t byteoff, float v) {
    asm volatile("ds_add_f32 %0, %1" :: "v"(byteoff), "v"(v));
}

__global__ __launch_bounds__(1024) void finalize_kernel(
    const float* __restrict__ gacc, float* __restrict__ out)
{
    __shared__ float mean_s[NCLS * MSTR];
    __shared__ float colstd[D];
    __shared__ float norms[NCLS];
    __shared__ float redSum[16], redMin[16];
    __shared__ float s_cov;

    const float* gSum = gacc;
    const float* gSq  = gacc + NCLS * D;
    const float* gCnt = gacc + 2 * NCLS * D;

    for (int d = threadIdx.x; d < D; d += 1024) colstd[d] = 0.0f;
    __syncthreads();

    for (int i = threadIdx.x; i < NCLS * D; i += 1024) {
        int c = i >> 6, d = i & 63;
        float cnt = gCnt[c];
        float m   = gSum[i] / cnt;
        float var = (gSq[i] - cnt * m * m) / (cnt - 1.0f);
        float sd  = sqrtf(fmaxf(var, 0.0f));
        mean_s[c * MSTR + d] = m;
        lds_fadd((uint32_t)(uintptr_t)(&colstd[d]), sd);
    }
    asm volatile("s_waitcnt lgkmcnt(0)" ::: "memory");
    __syncthreads();

    if (threadIdx.x < 64) {
        float v = colstd[threadIdx.x];
        v = v * v;
        for (int o = 32; o; o >>= 1) v += __shfl_down(v, o);
        if (threadIdx.x == 0) s_cov = v / (float)NCLS;
    }

    for (int c = threadIdx.x; c < NCLS; c += 1024) {
        const float4* mp = (const float4*)&mean_s[c * MSTR];
        float n = 0.0f;
        #pragma unroll
        for (int d4 = 0; d4 < D / 4; ++d4) {
            float4 a = mp[d4];
            n += a.x * a.x + a.y * a.y + a.z * a.z + a.w * a.w;
        }
        norms[c] = n;
    }
    __syncthreads();

    const int n_pairs = NCLS * (NCLS - 1) / 2;
    float lsum = 0.0f, lmin = INFINITY;
    for (int p = threadIdx.x; p < n_pairs; p += 1024) {
        int i = (int)((1.0f + sqrtf(1.0f + 8.0f * (float)p)) * 0.5f);
        while (i * (i - 1) / 2 > p) --i;
        while ((i + 1) * i / 2 <= p) ++i;
        int j = p - i * (i - 1) / 2;

        const float4* mi = (const float4*)&mean_s[i * MSTR];
        const float4* mj = (const float4*)&mean_s[j * MSTR];
        float dot = 0.0f;
        #pragma unroll
        for (int d4 = 0; d4 < D / 4; ++d4) {
            float4 a = mi[d4], b = mj[d4];
            dot += a.x * b.x + a.y * b.y + a.z * b.z + a.w * b.w;
        }
        float dist = norms[i] + norms[j] - 2.0f * dot;
        lsum += dist;
        lmin = fminf(lmin, dist);
    }

    for (int o = 32; o; o >>= 1) {
        lsum += __shfl_down(lsum, o);
        lmin = fminf(lmin, __shfl_down(lmin, o));
    }
    int ww = threadIdx.x >> 6;
    if ((threadIdx.x & 63) == 0) { redSum[ww] = lsum; redMin[ww] = lmin; }
    __syncthreads();

    if (threadIdx.x == 0) {
        float S = 0.0f, M = INFINITY;
        for (int k = 0; k < 16; ++k) { S += redSum[k]; M = fminf(M, redMin[k]); }
        float md  = S / (float)n_pairs;
        float cov = s_cov;
        float e   = 8.0f - md;
        float loss = 1.0f * cov + 0.1f * e * e;   // C_COEF = 0
        out[0] = loss;
        out[1] = md;
        out[2] = M;
        out[3] = cov;
    }
}

extern "C" void kernel_launch(void* const* d_in, const int* in_sizes, int n_in,
                              void* d_out, int out_size, void* d_ws, size_t ws_size,
                              hipStream_t stream) {
    const float* pred = (const float*)d_in[0];
    const int*   gidx = (const int*)d_in[1];
    float* out = (float*)d_out;
    int nrows = in_sizes[1];   // 2,000,000 rows

    const size_t partBytes = (size_t)GACC_FLOATS * G1 * sizeof(float);
    if (ws_size >= partBytes + GACC_FLOATS * sizeof(float)) {
        float* part = (float*)d_ws;
        float* gacc = part + (size_t)GACC_FLOATS * G1;
        seg_mfma_kernel<<<G1, BLK, 0, stream>>>(pred, gidx, part, gacc, nrows, 0);
        reduce_kernel<<<(GACC_FLOATS + 3) / 4, 256, 0, stream>>>(part, gacc);
        finalize_kernel<<<1, 1024, 0, stream>>>(gacc, out);
    } else {
        float* gacc = (float*)d_ws;
        hipMemsetAsync(gacc, 0, GACC_FLOATS * sizeof(float), stream);
        seg_mfma_kernel<<<G1, BLK, 0, stream>>>(pred, gidx, nullptr, gacc, nrows, 1);
        finalize_kernel<<<1, 1024, 0, stream>>>(gacc, out);
    }
}

// Round 4
// 304.543 us; speedup vs baseline: 4.3141x; 1.1087x over previous
//
#include <hip/hip_runtime.h>
#include <math.h>

#define NCLS 100
#define D 64
#define GACC_FLOATS (NCLS * D * 2 + NCLS)   // 12900: sums[6400] sq[6400] cnt[100]
#define KB1 768        // slab-groups per column-half
#define BLK 256
#define HPART 6400     // per-block partial floats: 100cls x 32col x {sum,sq}

typedef __attribute__((ext_vector_type(8)))  short bf16x8;
typedef __attribute__((ext_vector_type(16))) float f32x16;

#define ZV16 {0.f,0.f,0.f,0.f,0.f,0.f,0.f,0.f,0.f,0.f,0.f,0.f,0.f,0.f,0.f,0.f}

union B8 { uint32_t u[4]; bf16x8 v; };

// packed f32->bf16 RNE, 1 instruction for 2 values. Used for BOTH A and B so
// any within-pair order convention cancels in the dot product.
__device__ __forceinline__ uint32_t cvtpk(float lo, float hi) {
    uint32_t r;
    asm("v_cvt_pk_bf16_f32 %0, %1, %2" : "=v"(r) : "v"(lo), "v"(hi));
    return r;
}

__device__ __forceinline__ void global_fadd(float* p, float v) {
    asm volatile("global_atomic_add_f32 %0, %1, off"
                 :: "v"((uint64_t)(uintptr_t)p), "v"(v));
}

__device__ __forceinline__ void lds_fadd(uint32_t byteoff, float v) {
    asm volatile("ds_add_f32 %0, %1" :: "v"(byteoff), "v"(v));
}

// ---------------- Kernel 1: segmented sum/sumsq via one-hot MFMA ----------
// grid (KB1, 2): x = slab-group, y = column half (32 cols each).
// Per wave w: classes [32w,32w+32). A: row=lane&31, k=(lane>>5)*8+e.
// B: col=lane&31 (global col = 32h+col), same k.
// C/D: col=lane&31, row=(reg&3)+8*(reg>>2)+4*(lane>>5)  [validated in R3]
__global__ __launch_bounds__(BLK, 4) void seg_mfma_kernel(
    const float* __restrict__ pred, const int* __restrict__ idx,
    float* __restrict__ part, float* __restrict__ gacc,
    int nrows, int atomicPath)
{
    const int x     = blockIdx.x;
    const int h     = blockIdx.y;
    const int lane  = threadIdx.x & 63;
    const int w     = threadIdx.x >> 6;
    const int col   = lane & 31;
    const int kg    = lane >> 5;
    const int mycls = w * 32 + col;
    const int gcol  = h * 32 + col;

    f32x16 aS = ZV16, aQ = ZV16;

    const size_t nslab = (size_t)nrows >> 4;
    size_t s0 = (size_t)x * nslab / KB1;
    size_t s1 = ((size_t)x + 1) * nslab / KB1;

    for (size_t s = s0; s < s1; ++s) {
        const size_t kb = s << 4;
        const int* ip = idx + kb + (size_t)kg * 8;
        const int4 i0 = *(const int4*)ip;
        const int4 i1 = *(const int4*)(ip + 4);

        B8 ab;
        ab.u[0] = cvtpk(i0.x==mycls?1.f:0.f, i0.y==mycls?1.f:0.f);
        ab.u[1] = cvtpk(i0.z==mycls?1.f:0.f, i0.w==mycls?1.f:0.f);
        ab.u[2] = cvtpk(i1.x==mycls?1.f:0.f, i1.y==mycls?1.f:0.f);
        ab.u[3] = cvtpk(i1.z==mycls?1.f:0.f, i1.w==mycls?1.f:0.f);

        const float* pb = pred + ((kb + (size_t)kg * 8) << 6) + gcol;
        float v[8];
        #pragma unroll
        for (int e = 0; e < 8; ++e) v[e] = pb[(size_t)e * 64];   // 128B/half-wave

        B8 bv, bq;
        #pragma unroll
        for (int e = 0; e < 4; ++e) {
            bv.u[e] = cvtpk(v[2*e],        v[2*e+1]);
            bq.u[e] = cvtpk(v[2*e]*v[2*e], v[2*e+1]*v[2*e+1]);
        }
        aS = __builtin_amdgcn_mfma_f32_32x32x16_bf16(ab.v, bv.v, aS, 0, 0, 0);
        aQ = __builtin_amdgcn_mfma_f32_32x32x16_bf16(ab.v, bq.v, aQ, 0, 0, 0);
    }

    // tail rows (nrows % 16), last x-block of each half, masked
    if (x == KB1 - 1 && (nrows & 15)) {
        const size_t kb = nslab << 4;
        int c[8]; float v[8];
        #pragma unroll
        for (int e = 0; e < 8; ++e) {
            size_t kk = kb + (size_t)kg * 8 + e;
            bool ok = kk < (size_t)nrows;
            c[e] = ok ? idx[kk] : -1;
            v[e] = ok ? pred[(kk << 6) + gcol] : 0.0f;
        }
        B8 ab, bv, bq;
        #pragma unroll
        for (int e = 0; e < 4; ++e) {
            ab.u[e] = cvtpk(c[2*e]==mycls?1.f:0.f, c[2*e+1]==mycls?1.f:0.f);
            bv.u[e] = cvtpk(v[2*e],        v[2*e+1]);
            bq.u[e] = cvtpk(v[2*e]*v[2*e], v[2*e+1]*v[2*e+1]);
        }
        aS = __builtin_amdgcn_mfma_f32_32x32x16_bf16(ab.v, bv.v, aS, 0, 0, 0);
        aQ = __builtin_amdgcn_mfma_f32_32x32x16_bf16(ab.v, bq.v, aQ, 0, 0, 0);
    }

    // epilogue: coalesced per-block partials (or atomic fallback)
    if (!atomicPath) {
        float* pp = part + ((size_t)h * KB1 + x) * HPART;
        #pragma unroll
        for (int reg = 0; reg < 16; ++reg) {
            int row = (reg & 3) + 8 * (reg >> 2) + 4 * kg;
            int gm  = w * 32 + row;
            if (gm < NCLS) {
                pp[gm * 32 + col]        = aS[reg];   // lanes -> 128B contiguous
                pp[3200 + gm * 32 + col] = aQ[reg];
            }
        }
    } else {
        #pragma unroll
        for (int reg = 0; reg < 16; ++reg) {
            int row = (reg & 3) + 8 * (reg >> 2) + 4 * kg;
            int gm  = w * 32 + row;
            if (gm < NCLS) {
                global_fadd(&gacc[gm * D + gcol],        aS[reg]);
                global_fadd(&gacc[6400 + gm * D + gcol], aQ[reg]);
            }
        }
    }
}

// ---------------- Kernel 1b: class counts (LDS u32 histogram) -------------
__global__ __launch_bounds__(256) void hist_kernel(
    const int* __restrict__ idx, float* __restrict__ gcnt, int nrows)
{
    __shared__ uint32_t hh[NCLS];
    for (int i = threadIdx.x; i < NCLS; i += 256) hh[i] = 0u;
    __syncthreads();

    const int tid = blockIdx.x * 256 + threadIdx.x;
    const int stride = gridDim.x * 256;
    const int n4 = nrows >> 2;
    for (int i = tid; i < n4; i += stride) {
        int4 c = ((const int4*)idx)[i];
        atomicAdd(&hh[c.x], 1u); atomicAdd(&hh[c.y], 1u);
        atomicAdd(&hh[c.z], 1u); atomicAdd(&hh[c.w], 1u);
    }
    for (int i = (n4 << 2) + tid; i < nrows; i += stride)
        atomicAdd(&hh[idx[i]], 1u);
    __syncthreads();

    for (int i = threadIdx.x; i < NCLS; i += 256)
        if (hh[i]) global_fadd(&gcnt[i], (float)hh[i]);
}

// ---------------- Kernel 1c: reduce partials (lanes along pos) ------------
__global__ __launch_bounds__(256) void reduce_kernel(
    const float* __restrict__ part, float* __restrict__ gacc)
{
    int t = blockIdx.x * 256 + threadIdx.x;    // 0..12799
    if (t >= 2 * HPART) return;
    int h   = t / HPART;
    int pos = t - h * HPART;

    const float* p = part + (size_t)h * KB1 * HPART + pos;
    float s0 = 0.f, s1 = 0.f, s2 = 0.f, s3 = 0.f;
    int b = 0;
    for (; b + 4 <= KB1; b += 4) {
        s0 += p[(size_t)(b + 0) * HPART];
        s1 += p[(size_t)(b + 1) * HPART];
        s2 += p[(size_t)(b + 2) * HPART];
        s3 += p[(size_t)(b + 3) * HPART];
    }
    for (; b < KB1; ++b) s0 += p[(size_t)b * HPART];
    float s = (s0 + s1) + (s2 + s3);

    int isq = pos >= 3200;
    int lp  = pos - isq * 3200;
    int c   = lp >> 5;
    int d   = (lp & 31) + h * 32;
    gacc[isq * 6400 + c * D + d] = s;
}

// ---------------- Kernel 2: finalize (unchanged, verified) ----------------
#define MSTR 68

__global__ __launch_bounds__(1024) void finalize_kernel(
    const float* __restrict__ gacc, float* __restrict__ out)
{
    __shared__ float mean_s[NCLS * MSTR];
    __shared__ float colstd[D];
    __shared__ float norms[NCLS];
    __shared__ float redSum[16], redMin[16];
    __shared__ float s_cov;

    const float* gSum = gacc;
    const float* gSq  = gacc + NCLS * D;
    const float* gCnt = gacc + 2 * NCLS * D;

    for (int d = threadIdx.x; d < D; d += 1024) colstd[d] = 0.0f;
    __syncthreads();

    for (int i = threadIdx.x; i < NCLS * D; i += 1024) {
        int c = i >> 6, d = i & 63;
        float cnt = gCnt[c];
        float m   = gSum[i] / cnt;
        float var = (gSq[i] - cnt * m * m) / (cnt - 1.0f);
        float sd  = sqrtf(fmaxf(var, 0.0f));
        mean_s[c * MSTR + d] = m;
        lds_fadd((uint32_t)(uintptr_t)(&colstd[d]), sd);
    }
    asm volatile("s_waitcnt lgkmcnt(0)" ::: "memory");
    __syncthreads();

    if (threadIdx.x < 64) {
        float v = colstd[threadIdx.x];
        v = v * v;
        for (int o = 32; o; o >>= 1) v += __shfl_down(v, o);
        if (threadIdx.x == 0) s_cov = v / (float)NCLS;
    }

    for (int c = threadIdx.x; c < NCLS; c += 1024) {
        const float4* mp = (const float4*)&mean_s[c * MSTR];
        float n = 0.0f;
        #pragma unroll
        for (int d4 = 0; d4 < D / 4; ++d4) {
            float4 a = mp[d4];
            n += a.x * a.x + a.y * a.y + a.z * a.z + a.w * a.w;
        }
        norms[c] = n;
    }
    __syncthreads();

    const int n_pairs = NCLS * (NCLS - 1) / 2;
    float lsum = 0.0f, lmin = INFINITY;
    for (int p = threadIdx.x; p < n_pairs; p += 1024) {
        int i = (int)((1.0f + sqrtf(1.0f + 8.0f * (float)p)) * 0.5f);
        while (i * (i - 1) / 2 > p) --i;
        while ((i + 1) * i / 2 <= p) ++i;
        int j = p - i * (i - 1) / 2;

        const float4* mi = (const float4*)&mean_s[i * MSTR];
        const float4* mj = (const float4*)&mean_s[j * MSTR];
        float dot = 0.0f;
        #pragma unroll
        for (int d4 = 0; d4 < D / 4; ++d4) {
            float4 a = mi[d4], b = mj[d4];
            dot += a.x * b.x + a.y * b.y + a.z * b.z + a.w * b.w;
        }
        float dist = norms[i] + norms[j] - 2.0f * dot;
        lsum += dist;
        lmin = fminf(lmin, dist);
    }

    for (int o = 32; o; o >>= 1) {
        lsum += __shfl_down(lsum, o);
        lmin = fminf(lmin, __shfl_down(lmin, o));
    }
    int ww = threadIdx.x >> 6;
    if ((threadIdx.x & 63) == 0) { redSum[ww] = lsum; redMin[ww] = lmin; }
    __syncthreads();

    if (threadIdx.x == 0) {
        float S = 0.0f, M = INFINITY;
        for (int k = 0; k < 16; ++k) { S += redSum[k]; M = fminf(M, redMin[k]); }
        float md  = S / (float)n_pairs;
        float cov = s_cov;
        float e   = 8.0f - md;
        float loss = 1.0f * cov + 0.1f * e * e;   // C_COEF = 0
        out[0] = loss;
        out[1] = md;
        out[2] = M;
        out[3] = cov;
    }
}

extern "C" void kernel_launch(void* const* d_in, const int* in_sizes, int n_in,
                              void* d_out, int out_size, void* d_ws, size_t ws_size,
                              hipStream_t stream) {
    const float* pred = (const float*)d_in[0];
    const int*   gidx = (const int*)d_in[1];
    float* out = (float*)d_out;
    int nrows = in_sizes[1];   // 2,000,000 rows

    const size_t partFloats = (size_t)2 * KB1 * HPART;   // 9,830,400 = 39.32 MB
    dim3 grid1(KB1, 2);

    if (ws_size >= (partFloats + GACC_FLOATS) * sizeof(float)) {
        float* part = (float*)d_ws;
        float* gacc = part + partFloats;
        hipMemsetAsync(gacc, 0, GACC_FLOATS * sizeof(float), stream);
        seg_mfma_kernel<<<grid1, BLK, 0, stream>>>(pred, gidx, part, gacc, nrows, 0);
        hist_kernel<<<256, 256, 0, stream>>>(gidx, gacc + 2 * NCLS * D, nrows);
        reduce_kernel<<<(2 * HPART + 255) / 256, 256, 0, stream>>>(part, gacc);
        finalize_kernel<<<1, 1024, 0, stream>>>(gacc, out);
    } else {
        float* gacc = (float*)d_ws;
        hipMemsetAsync(gacc, 0, GACC_FLOATS * sizeof(float), stream);
        seg_mfma_kernel<<<grid1, BLK, 0, stream>>>(pred, gidx, nullptr, gacc, nrows, 1);
        hist_kernel<<<256, 256, 0, stream>>>(gidx, gacc + 2 * NCLS * D, nrows);
        finalize_kernel<<<1, 1024, 0, stream>>>(gacc, out);
    }
}